// Round 1
// baseline (22468.073 us; speedup 1.0000x reference)
//
#include <hip/hip_runtime.h>

#define NB 256
#define NT 8192
#define NI 6
#define NU 64
#define NM 16
#define UNFOLDS 6
#define EPSF 1e-8f
#define LOG2E 1.44269504088896340736f

__device__ __forceinline__ float fexp2(float x) { return __builtin_amdgcn_exp2f(x); }
__device__ __forceinline__ float frcp(float x)  { return __builtin_amdgcn_rcpf(x); }

// xor-butterfly sum across the 8 chunk-lanes (lanes l, l^1, l^2, l^4 share a dst j)
template <int PAT>
__device__ __forceinline__ float swz(float x) {
  return __int_as_float(__builtin_amdgcn_ds_swizzle(__float_as_int(x), PAT));
}
__device__ __forceinline__ float red8(float x) {
  x += swz<0x041F>(x);  // xor 1
  x += swz<0x081F>(x);  // xor 2
  x += swz<0x101F>(x);  // xor 4
  return x;
}

// One block = one batch row. 512 threads: thread = (j = tid>>3 dst unit, c = tid&7 src chunk).
// Lane (j,c) accumulates src rows i in [8c, 8c+8) for dst column j; weights live in VGPRs.
// Cross-wave state = the 64-float v vector, double-buffered in LDS, 1 barrier per unfold.
__global__ __launch_bounds__(512, 2) void ltc_kernel(
    const float* __restrict__ x,
    const float* __restrict__ gleak, const float* __restrict__ vleak,
    const float* __restrict__ cm,
    const float* __restrict__ sigma, const float* __restrict__ mu,
    const float* __restrict__ w,     const float* __restrict__ erev,
    const float* __restrict__ ssigma, const float* __restrict__ smu,
    const float* __restrict__ sw_,    const float* __restrict__ serev,
    const float* __restrict__ iw, const float* __restrict__ ib,
    const float* __restrict__ ow_, const float* __restrict__ ob_,
    float* __restrict__ out)
{
  const int tid = threadIdx.x;
  const int b   = blockIdx.x;
  const int j   = tid >> 3;   // dst unit 0..63
  const int c   = tid & 7;    // src chunk 0..7
  const int i0  = c * 8;

  // ---- preload + pre-transform recurrent weights (once per 8192 steps) ----
  // sigmoid((v-mu)*sigma) = 1 / (1 + exp2(fma(v, a1, a0))),  a1=-sigma*log2e, a0=mu*sigma*log2e
  float a1[8], a0[8], wv[8], we[8];
#pragma unroll
  for (int k = 0; k < 8; ++k) {
    const int idx = (i0 + k) * NU + j;
    const float sg = sigma[idx] * LOG2E;
    a1[k] = -sg;
    a0[k] = mu[idx] * sg;
    wv[k] = w[idx];
    we[k] = w[idx] * erev[idx];
  }
  // sensory synapse: lane handles src i == c (c >= 6 contributes exactly 0)
  float b1 = 0.f, b0 = 0.f, swv = 0.f, swe = 0.f;
  if (c < NI) {
    const int idx = c * NU + j;
    const float sg = ssigma[idx] * LOG2E;
    b1 = -sg * iw[c];
    b0 = sg * (smu[idx] - ib[c]);
    swv = sw_[idx];
    swe = swv * serev[idx];
  }
  const float gl   = gleak[j];
  const float glvl = gl * vleak[j];
  const float cmt  = cm[j] * (float)UNFOLDS;   // cm / (elapsed/unfolds), elapsed=1
  const float ow   = (j < NM) ? ow_[j] : 0.f;
  const float ob   = (j < NM) ? ob_[j] : 0.f;

  __shared__ float vbuf[2][NU];
  float v = 0.f;                 // this lane's dst-unit state (replicated across its 8 chunk-lanes)
  if (c == 0) vbuf[0][j] = 0.f;
  __syncthreads();

  const float* xp = x + (size_t)b * NT * NI + (c < NI ? c : 0);
  float* op = out + (size_t)b * NT * NM;

  float xv = xp[0];
  int p = 0;

  for (int t = 0; t < NT; ++t) {
    // prefetch next timestep's input (hidden under ~6 unfolds of compute)
    const int tn = (t + 1 < NT) ? (t + 1) : t;
    const float xnext = xp[tn * NI];

    // ---- sensory activations (constant across the 6 unfolds) ----
    const float es   = fexp2(fmaf(xv, b1, b0));
    const float ssig = frcp(1.f + es);
    const float num_s = red8(swe * ssig);
    const float den_s = red8(swv * ssig);

    // ---- fused semi-implicit Euler unfolds ----
    for (int u = 0; u < UNFOLDS; ++u) {
      float vv[8];
      *(float4*)&vv[0] = *(const float4*)&vbuf[p][i0];
      *(float4*)&vv[4] = *(const float4*)&vbuf[p][i0 + 4];
      float an = 0.f, ad = 0.f;
#pragma unroll
      for (int k = 0; k < 8; ++k) {
        const float e = fexp2(fmaf(vv[k], a1[k], a0[k]));
        const float s = frcp(1.f + e);
        an = fmaf(we[k], s, an);
        ad = fmaf(wv[k], s, ad);
      }
      an = red8(an);
      ad = red8(ad);
      const float num = fmaf(cmt, v, glvl) + an + num_s;
      const float den = cmt + gl + ad + den_s;
      v = num * frcp(den + EPSF);
      if (c == 0) vbuf[p ^ 1][j] = v;
      __syncthreads();
      p ^= 1;
    }

    // ---- map_outputs: first NM motor neurons ----
    if (c == 0 && j < NM) op[t * NM + j] = fmaf(v, ow, ob);
    xv = xnext;
  }
}

extern "C" void kernel_launch(void* const* d_in, const int* in_sizes, int n_in,
                              void* d_out, int out_size, void* d_ws, size_t ws_size,
                              hipStream_t stream) {
  (void)in_sizes; (void)n_in; (void)d_ws; (void)ws_size; (void)out_size;
  const float* x      = (const float*)d_in[0];
  const float* gleak  = (const float*)d_in[1];
  const float* vleak  = (const float*)d_in[2];
  const float* cm     = (const float*)d_in[3];
  const float* sigma  = (const float*)d_in[4];
  const float* mu     = (const float*)d_in[5];
  const float* w      = (const float*)d_in[6];
  const float* erev   = (const float*)d_in[7];
  const float* ssig   = (const float*)d_in[8];
  const float* smu    = (const float*)d_in[9];
  const float* sw     = (const float*)d_in[10];
  const float* serev  = (const float*)d_in[11];
  const float* iw     = (const float*)d_in[12];
  const float* ib     = (const float*)d_in[13];
  const float* ow     = (const float*)d_in[14];
  const float* ob     = (const float*)d_in[15];
  float* out = (float*)d_out;

  ltc_kernel<<<dim3(NB), dim3(512), 0, stream>>>(
      x, gleak, vleak, cm, sigma, mu, w, erev,
      ssig, smu, sw, serev, iw, ib, ow, ob, out);
}

// Round 2
// 17803.169 us; speedup vs baseline: 1.2620x; 1.2620x over previous
//
#include <hip/hip_runtime.h>

#define NB 256
#define NT 8192
#define NI 6
#define NU 64
#define NM 16
#define UNFOLDS 6
#define EPSF 1e-8f
#define LOG2E 1.44269504088896340736f

__device__ __forceinline__ float fexp2(float x) { return __builtin_amdgcn_exp2f(x); }
__device__ __forceinline__ float frcp(float x)  { return __builtin_amdgcn_rcpf(x); }

// 8-lane all-reduce sum via DPP (lanes grouped 8-aligned within a wave).
// Stage1 xor1: quad_perm [1,0,3,2] = 0xB1; Stage2 xor2: quad_perm [2,3,0,1] = 0x4E;
// Stage3: row_half_mirror (l -> l^7, other quad, which holds that quad's sum) = 0x141.
template <int CTRL>
__device__ __forceinline__ float dpp_add(float x) {
  int t = __builtin_amdgcn_update_dpp(0, __float_as_int(x), CTRL, 0xF, 0xF, true);
  return x + __int_as_float(t);
}
__device__ __forceinline__ float red8(float x) {
  x = dpp_add<0xB1>(x);
  x = dpp_add<0x4E>(x);
  x = dpp_add<0x141>(x);
  return x;
}

// LDS-only barrier: drains lgkmcnt but NOT vmcnt, so the x-prefetch and the
// output stores stay in flight across unfold barriers (no vmem drain).
__device__ __forceinline__ void lds_barrier() {
  asm volatile("s_waitcnt lgkmcnt(0)\n\ts_barrier" ::: "memory");
}

// One block = one batch row. 512 threads: thread = (j = tid>>3 dst unit, c = tid&7 src chunk).
__global__ __launch_bounds__(512, 2) void ltc_kernel(
    const float* __restrict__ x,
    const float* __restrict__ gleak, const float* __restrict__ vleak,
    const float* __restrict__ cm,
    const float* __restrict__ sigma, const float* __restrict__ mu,
    const float* __restrict__ w,     const float* __restrict__ erev,
    const float* __restrict__ ssigma, const float* __restrict__ smu,
    const float* __restrict__ sw_,    const float* __restrict__ serev,
    const float* __restrict__ iw, const float* __restrict__ ib,
    const float* __restrict__ ow_, const float* __restrict__ ob_,
    float* __restrict__ out)
{
  const int tid = threadIdx.x;
  const int b   = blockIdx.x;
  const int j   = tid >> 3;   // dst unit 0..63
  const int c   = tid & 7;    // src chunk 0..7
  const int i0  = c * 8;

  // ---- preload + pre-transform recurrent weights (once per 8192 steps) ----
  // sigmoid((v-mu)*sigma) = 1 / (1 + exp2(fma(v, a1, a0))),  a1=-sigma*log2e, a0=mu*sigma*log2e
  float a1[8], a0[8], wv[8], we[8];
#pragma unroll
  for (int k = 0; k < 8; ++k) {
    const int idx = (i0 + k) * NU + j;
    const float sg = sigma[idx] * LOG2E;
    a1[k] = -sg;
    a0[k] = mu[idx] * sg;
    wv[k] = w[idx];
    we[k] = w[idx] * erev[idx];
  }
  // sensory synapse: lane handles src i == c (c >= 6 contributes exactly 0)
  float b1 = 0.f, b0 = 0.f, swv = 0.f, swe = 0.f;
  if (c < NI) {
    const int idx = c * NU + j;
    const float sg = ssigma[idx] * LOG2E;
    b1 = -sg * iw[c];
    b0 = sg * (smu[idx] - ib[c]);
    swv = sw_[idx];
    swe = swv * serev[idx];
  }
  const float gl   = gleak[j];
  const float glvl = gl * vleak[j];
  const float cmt  = cm[j] * (float)UNFOLDS;   // cm / (elapsed/unfolds), elapsed=1
  const float ow   = (j < NM) ? ow_[j] : 0.f;
  const float ob   = (j < NM) ? ob_[j] : 0.f;

  __shared__ float vbuf[2][NU];
  float v = 0.f;                 // this lane's dst-unit state (replicated across its 8 chunk-lanes)
  if (c == 0) vbuf[0][j] = 0.f;
  __syncthreads();

  const float* xp = x + (size_t)b * NT * NI + (c < NI ? c : 0);
  float* op = out + (size_t)b * NT * NM;

  float xv = xp[0];

  for (int t = 0; t < NT; ++t) {
    // prefetch next timestep's input (hidden under ~6 unfolds of compute;
    // never drained early now that barriers are LDS-only)
    const int tn = (t + 1 < NT) ? (t + 1) : t;
    const float xnext = xp[tn * NI];

    // ---- sensory activations (constant across the 6 unfolds) ----
    const float es   = fexp2(fmaf(xv, b1, b0));
    const float ssig = frcp(1.f + es);
    const float num_s = red8(swe * ssig);
    const float den_s = red8(swv * ssig);
    const float num_base = glvl + num_s;               // hoisted per step
    const float den_base = cmt + gl + den_s + EPSF;    // hoisted per step

    // ---- fused semi-implicit Euler unfolds (fully unrolled, static dbuf) ----
#pragma unroll
    for (int u = 0; u < UNFOLDS; ++u) {
      const int p = u & 1;
      float vv[8];
      *(float4*)&vv[0] = *(const float4*)&vbuf[p][i0];
      *(float4*)&vv[4] = *(const float4*)&vbuf[p][i0 + 4];
      float an = 0.f, ad = 0.f;
#pragma unroll
      for (int k = 0; k < 8; ++k) {
        const float e = fexp2(fmaf(vv[k], a1[k], a0[k]));
        const float s = frcp(1.f + e);
        an = fmaf(we[k], s, an);
        ad = fmaf(wv[k], s, ad);
      }
      an = red8(an);
      ad = red8(ad);
      const float den = den_base + ad;
      const float num = fmaf(cmt, v, num_base) + an;
      v = num * frcp(den);
      if (c == 0) vbuf[p ^ 1][j] = v;
      lds_barrier();
    }

    // ---- map_outputs: first NM motor neurons ----
    if (c == 0 && j < NM) op[t * NM + j] = fmaf(v, ow, ob);
    xv = xnext;
  }
}

extern "C" void kernel_launch(void* const* d_in, const int* in_sizes, int n_in,
                              void* d_out, int out_size, void* d_ws, size_t ws_size,
                              hipStream_t stream) {
  (void)in_sizes; (void)n_in; (void)d_ws; (void)ws_size; (void)out_size;
  const float* x      = (const float*)d_in[0];
  const float* gleak  = (const float*)d_in[1];
  const float* vleak  = (const float*)d_in[2];
  const float* cm     = (const float*)d_in[3];
  const float* sigma  = (const float*)d_in[4];
  const float* mu     = (const float*)d_in[5];
  const float* w      = (const float*)d_in[6];
  const float* erev   = (const float*)d_in[7];
  const float* ssig   = (const float*)d_in[8];
  const float* smu    = (const float*)d_in[9];
  const float* sw     = (const float*)d_in[10];
  const float* serev  = (const float*)d_in[11];
  const float* iw     = (const float*)d_in[12];
  const float* ib     = (const float*)d_in[13];
  const float* ow     = (const float*)d_in[14];
  const float* ob     = (const float*)d_in[15];
  float* out = (float*)d_out;

  ltc_kernel<<<dim3(NB), dim3(512), 0, stream>>>(
      x, gleak, vleak, cm, sigma, mu, w, erev,
      ssig, smu, sw, serev, iw, ib, ow, ob, out);
}